// Round 3
// baseline (525.675 us; speedup 1.0000x reference)
//
#include <hip/hip_runtime.h>

#define Tn 200
#define Dn 64
#define Hn 64

typedef _Float16 half2v __attribute__((ext_vector_type(2)));
typedef _Float16 half8v __attribute__((ext_vector_type(8)));
typedef float    f32x4  __attribute__((ext_vector_type(4)));
typedef unsigned int uint;

__device__ __forceinline__ float fast_sigmoid(float v) {
    return __builtin_amdgcn_rcpf(1.0f + __expf(-v));
}
__device__ __forceinline__ float fast_tanh(float v) {
    return 1.0f - 2.0f * __builtin_amdgcn_rcpf(1.0f + __expf(2.0f * v));
}
// Intra-wave LDS ordering (wave64 lockstep): drain lgkm queue + compiler fence.
__device__ __forceinline__ void wave_lds_fence() {
    asm volatile("s_waitcnt lgkmcnt(0)" ::: "memory");
}
__device__ __forceinline__ uint pk16(float a, float b) {
    return __builtin_bit_cast(uint, __builtin_amdgcn_cvt_pkrtz(a, b));
}

// ============================================================================
// Fully fused AUGRU, 16 batch rows per wave, swapped-operand MFMA.
//
// Orientation: D' = A'(W^T) x B'(state^T):
//   A'-frag: lane holds W[k][16*T + (l&15)], k = (l>>4)*8 + e   (per 16-gate tile T)
//   B'-frag: lane holds S[m = l&15][k = (l>>4)*8 + e]           (S = [x;h] or [x;r*h])
//   D'-frag: lane holds G[n = 16*T + 4*(l>>4) + reg][m = l&15]
// => every gate value for row m lives in lanes {m, m+16, m+32, m+48}, and the
//    elementwise GRU update is 100% lane-local. h / r*h only need a tiny
//    4-lane-group transpose through 2.3 KB of LDS to become B'-frags.
//
// K=128 chain: kc=0,1 -> x part (bx0,bx1), kc=2,3 -> h part (bh0,bh1), so the
// x-projection is fused into the same MFMA chain (no P workspace at all).
//
// LDS transpose layout: row m stride 36 dwords (16B-aligned, bank-spread).
//   write: value pair (k0, k0+1), k0 = 16*T + 4*kq + 2*p  -> dword m*36 + 8*T + 2*kq + p
//   read : B'-frag k = kq*8 + e -> uint4 at dword m*36 + 4*kq (+16 for k>=32)
// ============================================================================

#define MFMA16(a, b, c) __builtin_amdgcn_mfma_f32_16x16x32_f16(a, b, c, 0, 0, 0)

#define AUGRU_STEP(q0, q1, q2, q3, af, tcur)                                    \
  {                                                                             \
    uint4 ux;                                                                   \
    ux.x = pk16(q0.x, q0.y); ux.y = pk16(q0.z, q0.w);                           \
    ux.z = pk16(q1.x, q1.y); ux.w = pk16(q1.z, q1.w);                           \
    const half8v bx0 = __builtin_bit_cast(half8v, ux);                          \
    ux.x = pk16(q2.x, q2.y); ux.y = pk16(q2.z, q2.w);                           \
    ux.z = pk16(q3.x, q3.y); ux.w = pk16(q3.z, q3.w);                           \
    const half8v bx1 = __builtin_bit_cast(half8v, ux);                          \
    const float uf = 1.0f - af;                                                 \
    { /* prefetch X/att for t+2 into the same named slot */                     \
      const int tp = min(tcur + 2, Lmax - 1);                                   \
      if (tp < len_m) {                                                         \
        const float* xr = xb + (size_t)tp * Dn + kq * 8;                        \
        q0 = *(const float4*)(xr);      q1 = *(const float4*)(xr + 4);          \
        q2 = *(const float4*)(xr + 32); q3 = *(const float4*)(xr + 36);         \
      }                                                                         \
      af = ab[tp];                                                              \
    }                                                                           \
    f32x4 R[4], U[4];                                                           \
    _Pragma("unroll")                                                           \
    for (int T = 0; T < 4; ++T) {                                               \
      f32x4 acc = Bru[T];                                                       \
      acc = MFMA16(Aru[T][0], bx0, acc);                                        \
      acc = MFMA16(Aru[T][1], bx1, acc);                                        \
      acc = MFMA16(Aru[T][2], bh0, acc);                                        \
      acc = MFMA16(Aru[T][3], bh1, acc);                                        \
      R[T] = acc;                                                               \
    }                                                                           \
    _Pragma("unroll")                                                           \
    for (int T = 0; T < 4; ++T) {                                               \
      f32x4 acc = Bru[T + 4];                                                   \
      acc = MFMA16(Aru[T + 4][0], bx0, acc);                                    \
      acc = MFMA16(Aru[T + 4][1], bx1, acc);                                    \
      acc = MFMA16(Aru[T + 4][2], bh0, acc);                                    \
      acc = MFMA16(Aru[T + 4][3], bh1, acc);                                    \
      U[T] = acc;                                                               \
    }                                                                           \
    /* r = sigmoid, r*h, pack -> LDS transpose buffer */                        \
    _Pragma("unroll")                                                           \
    for (int T = 0; T < 4; ++T) {                                               \
      const float rh0 = fast_sigmoid(R[T][0]) * hs[T * 4 + 0];                  \
      const float rh1 = fast_sigmoid(R[T][1]) * hs[T * 4 + 1];                  \
      const float rh2 = fast_sigmoid(R[T][2]) * hs[T * 4 + 2];                  \
      const float rh3 = fast_sigmoid(R[T][3]) * hs[T * 4 + 3];                  \
      s_tr[lm * 36 + 8 * T + 2 * kq + 0] = pk16(rh0, rh1);                      \
      s_tr[lm * 36 + 8 * T + 2 * kq + 1] = pk16(rh2, rh3);                      \
    }                                                                           \
    /* u-path VALU runs under the LDS write->read shadow */                     \
    float uh[16];                                                               \
    _Pragma("unroll")                                                           \
    for (int i = 0; i < 16; ++i) uh[i] = uf * fast_sigmoid(U[i >> 2][i & 3]);   \
    wave_lds_fence();                                                           \
    const half8v brh0 = __builtin_bit_cast(half8v,                              \
        *(const uint4*)&s_tr[lm * 36 + 4 * kq]);                                \
    const half8v brh1 = __builtin_bit_cast(half8v,                              \
        *(const uint4*)&s_tr[lm * 36 + 16 + 4 * kq]);                           \
    _Pragma("unroll")                                                           \
    for (int T = 0; T < 4; ++T) {                                               \
      f32x4 acc = Bc[T];                                                        \
      acc = MFMA16(Ac[T][0], bx0, acc);                                         \
      acc = MFMA16(Ac[T][1], bx1, acc);                                         \
      acc = MFMA16(Ac[T][2], brh0, acc);                                        \
      acc = MFMA16(Ac[T][3], brh1, acc);                                        \
      _Pragma("unroll")                                                         \
      for (int r = 0; r < 4; ++r) {                                             \
        const float cg = fast_tanh(acc[r]);                                     \
        hs[T * 4 + r] = cg + uh[T * 4 + r] * (hs[T * 4 + r] - cg);              \
      }                                                                         \
    }                                                                           \
    if (tcur < len_m) {                                                         \
      float* orow = out + ((size_t)brow * Tn + tcur) * Hn;                      \
      _Pragma("unroll")                                                         \
      for (int T = 0; T < 4; ++T) {                                             \
        orow[16 * T + 4 * kq + 0] = hs[T * 4 + 0];                              \
        orow[16 * T + 4 * kq + 1] = hs[T * 4 + 1];                              \
        orow[16 * T + 4 * kq + 2] = hs[T * 4 + 2];                              \
        orow[16 * T + 4 * kq + 3] = hs[T * 4 + 3];                              \
      }                                                                         \
    }                                                                           \
    /* h -> B'-frag for next step (same buffer; DS ops are in-order per wave,   \
       and brh reads completed before the cand MFMAs consumed them) */          \
    _Pragma("unroll")                                                           \
    for (int T = 0; T < 4; ++T) {                                               \
      s_tr[lm * 36 + 8 * T + 2 * kq + 0] = pk16(hs[T * 4 + 0], hs[T * 4 + 1]);  \
      s_tr[lm * 36 + 8 * T + 2 * kq + 1] = pk16(hs[T * 4 + 2], hs[T * 4 + 3]);  \
    }                                                                           \
    wave_lds_fence();                                                           \
    bh0 = __builtin_bit_cast(half8v, *(const uint4*)&s_tr[lm * 36 + 4 * kq]);   \
    bh1 = __builtin_bit_cast(half8v,                                            \
        *(const uint4*)&s_tr[lm * 36 + 16 + 4 * kq]);                           \
  }

__global__ __launch_bounds__(64, 1)
void augru_fused16(const float* __restrict__ x,    // [B,T,64]
                   const int*   __restrict__ slen, // [B]
                   const float* __restrict__ att,  // [B,T]
                   const float* __restrict__ gk,   // [128][128]
                   const float* __restrict__ gb,   // [128]
                   const float* __restrict__ ck,   // [128][64]
                   const float* __restrict__ cb,   // [64]
                   float*       __restrict__ out,  // [B,T,64]
                   int B)
{
    const int lane = threadIdx.x;
    const int lm = lane & 15;
    const int kq = lane >> 4;
    const int b0 = blockIdx.x * 16;
    const int brow  = b0 + lm;
    const int browc = min(brow, B - 1);
    const int len_m = (brow < B) ? slen[brow] : 0;

    // wave-wide max sequence length in this 16-row group
    int Lmax = len_m;
#pragma unroll
    for (int off = 32; off; off >>= 1) Lmax = max(Lmax, __shfl_xor(Lmax, off));

    __shared__ uint s_tr[16 * 36];   // 2304 B transpose scratch

    // ---- persistent weight A'-fragments (W^T) + bias C-inits ----
    half8v Aru[8][4];   // gate tiles T=0..7 (r: 0..3, u: 4..7), kc=0..3 (K=128)
    f32x4  Bru[8];
#pragma unroll
    for (int T = 0; T < 8; ++T) {
#pragma unroll
        for (int kc = 0; kc < 4; ++kc) {
            half8v f;
#pragma unroll
            for (int e = 0; e < 8; ++e)
                f[e] = (_Float16)gk[(kc * 32 + kq * 8 + e) * 128 + 16 * T + lm];
            Aru[T][kc] = f;
        }
        Bru[T] = f32x4{gb[16 * T + 4 * kq + 0], gb[16 * T + 4 * kq + 1],
                       gb[16 * T + 4 * kq + 2], gb[16 * T + 4 * kq + 3]};
    }
    half8v Ac[4][4];    // candidate tiles T=0..3
    f32x4  Bc[4];
#pragma unroll
    for (int T = 0; T < 4; ++T) {
#pragma unroll
        for (int kc = 0; kc < 4; ++kc) {
            half8v f;
#pragma unroll
            for (int e = 0; e < 8; ++e)
                f[e] = (_Float16)ck[(kc * 32 + kq * 8 + e) * 64 + 16 * T + lm];
            Ac[T][kc] = f;
        }
        Bc[T] = f32x4{cb[16 * T + 4 * kq + 0], cb[16 * T + 4 * kq + 1],
                      cb[16 * T + 4 * kq + 2], cb[16 * T + 4 * kq + 3]};
    }

    const float* xb = x   + (size_t)browc * Tn * Dn;
    const float* ab = att + (size_t)browc * Tn;

    // ---- state: h in D'-layout, lane-local; B'-frags of h (zero at t=0) ----
    float hs[16];
#pragma unroll
    for (int i = 0; i < 16; ++i) hs[i] = 0.0f;
    half8v bh0 = half8v{0}, bh1 = half8v{0};

    // ---- 2-deep named X/att prefetch slots ----
    float4 qA0{}, qA1{}, qA2{}, qA3{}, qB0{}, qB1{}, qB2{}, qB3{};
    float aA = 0.f, aB = 0.f;

    if (Lmax > 0) {
        if (0 < len_m) {
            const float* xr = xb + kq * 8;
            qA0 = *(const float4*)(xr);      qA1 = *(const float4*)(xr + 4);
            qA2 = *(const float4*)(xr + 32); qA3 = *(const float4*)(xr + 36);
        }
        aA = ab[0];
        const int t1 = min(1, Lmax - 1);
        if (t1 < len_m) {
            const float* xr = xb + (size_t)t1 * Dn + kq * 8;
            qB0 = *(const float4*)(xr);      qB1 = *(const float4*)(xr + 4);
            qB2 = *(const float4*)(xr + 32); qB3 = *(const float4*)(xr + 36);
        }
        aB = ab[t1];

        int t = 0;
        for (;;) {
            AUGRU_STEP(qA0, qA1, qA2, qA3, aA, t);
            if (++t >= Lmax) break;
            AUGRU_STEP(qB0, qB1, qB2, qB3, aB, t);
            if (++t >= Lmax) break;
        }
    }

    // ---- zero tails: out[b, len:T, :] = 0, all 64 lanes per row ----
#pragma unroll 1
    for (int mm = 0; mm < 16; ++mm) {
        const int row = b0 + mm;
        if (row >= B) break;
        const int L = __shfl(len_m, mm);
        float* tail = out + ((size_t)row * Tn + L) * Hn;
        const int total = (Tn - L) * Hn;
        for (int i = lane * 4; i < total; i += 256) {
            *(float4*)(tail + i) = make_float4(0.f, 0.f, 0.f, 0.f);
        }
    }
}

extern "C" void kernel_launch(void* const* d_in, const int* in_sizes, int n_in,
                              void* d_out, int out_size, void* d_ws, size_t ws_size,
                              hipStream_t stream) {
    const float* x    = (const float*)d_in[0];
    const int*   slen = (const int*)  d_in[1];
    const float* att  = (const float*)d_in[2];
    const float* gk   = (const float*)d_in[3];
    const float* gb   = (const float*)d_in[4];
    const float* ck   = (const float*)d_in[5];
    const float* cb   = (const float*)d_in[6];
    float* out = (float*)d_out;

    const int B = in_sizes[1];  // 2048
    const int grid = (B + 15) / 16;
    augru_fused16<<<grid, 64, 0, stream>>>(x, slen, att, gk, gb, ck, cb, out, B);
}

// Round 4
// 418.902 us; speedup vs baseline: 1.2549x; 1.2549x over previous
//
#include <hip/hip_runtime.h>

#define Tn 200
#define Dn 64
#define Hn 64

typedef _Float16 half8v __attribute__((ext_vector_type(8)));
typedef float    f32x4  __attribute__((ext_vector_type(4)));
typedef unsigned int uint;

__device__ __forceinline__ float fast_sigmoid(float v) {
    return __builtin_amdgcn_rcpf(1.0f + __expf(-v));
}
__device__ __forceinline__ float fast_tanh(float v) {
    return 1.0f - 2.0f * __builtin_amdgcn_rcpf(1.0f + __expf(2.0f * v));
}
__device__ __forceinline__ uint pk16(float a, float b) {
    return __builtin_bit_cast(uint, __builtin_amdgcn_cvt_pkrtz(a, b));
}

#define MFMA16(a, b, c) __builtin_amdgcn_mfma_f32_16x16x32_f16(a, b, c, 0, 0, 0)

// ============================================================================
// Fully fused AUGRU: 16 batch rows per BLOCK, 4 waves cooperating.
// Wave w owns gate/cand columns [16w, 16w+16): 3 MFMA tiles (r,u,c) x 4 K-chunks
// = 12 MFMAs/step/wave. Swapped-operand MFMA layout (verified in R3):
//   A'(weights): lane holds W[k = (l>>4)*8+e][16w + (l&15)]
//   B'(state):   lane holds S[m = l&15][k = (l>>4)*8+e]
//   D'(gates):   lane holds G[col = 16w + 4*(l>>4)+reg][row m = l&15]
// Cross-wave exchange of r*h and h via 2x 2.3KB LDS transpose buffers,
// 2 __syncthreads per step. Hazards: each buffer's reads complete before the
// consuming MFMAs (compiler lgkm waits), which precede the next barrier, so
// 2 barriers/step are sufficient (see R4 notes).
// x-part MFMAs issue before h-part => h-dependent chains are only 2-deep.
// ============================================================================

#define AUGRU_STEP(q0, q1, q2, q3, af, tcur)                                    \
  {                                                                             \
    uint4 ux;                                                                   \
    ux.x = pk16(q0.x, q0.y); ux.y = pk16(q0.z, q0.w);                           \
    ux.z = pk16(q1.x, q1.y); ux.w = pk16(q1.z, q1.w);                           \
    const half8v bx0 = __builtin_bit_cast(half8v, ux);                          \
    ux.x = pk16(q2.x, q2.y); ux.y = pk16(q2.z, q2.w);                           \
    ux.z = pk16(q3.x, q3.y); ux.w = pk16(q3.z, q3.w);                           \
    const half8v bx1 = __builtin_bit_cast(half8v, ux);                          \
    const float uf = 1.0f - af;                                                 \
    { /* prefetch X/att for t+2 into the same named slot */                     \
      const int tp = min(tcur + 2, Lmax - 1);                                   \
      if (tp < len_m) {                                                         \
        const float* xr = xb + (size_t)tp * Dn + kq * 8;                        \
        q0 = *(const float4*)(xr);      q1 = *(const float4*)(xr + 4);          \
        q2 = *(const float4*)(xr + 32); q3 = *(const float4*)(xr + 36);         \
      }                                                                         \
      af = ab[tp];                                                              \
    }                                                                           \
    f32x4 R = biasR, U = biasU, C = biasC;                                      \
    /* x-part first (independent of h) */                                       \
    R = MFMA16(Ar[0], bx0, R);  R = MFMA16(Ar[1], bx1, R);                      \
    U = MFMA16(Au[0], bx0, U);  U = MFMA16(Au[1], bx1, U);                      \
    C = MFMA16(Acn[0], bx0, C); C = MFMA16(Acn[1], bx1, C);                     \
    /* h-part (bh frags from end of previous step) */                           \
    R = MFMA16(Ar[2], bh0, R);  R = MFMA16(Ar[3], bh1, R);                      \
    U = MFMA16(Au[2], bh0, U);  U = MFMA16(Au[3], bh1, U);                      \
    s_rh[trw + 0] = pk16(fast_sigmoid(R[0]) * hs4[0],                           \
                         fast_sigmoid(R[1]) * hs4[1]);                          \
    s_rh[trw + 1] = pk16(fast_sigmoid(R[2]) * hs4[2],                           \
                         fast_sigmoid(R[3]) * hs4[3]);                          \
    /* u-path VALU runs under the LDS/barrier shadow */                         \
    const float uh0 = uf * fast_sigmoid(U[0]);                                  \
    const float uh1 = uf * fast_sigmoid(U[1]);                                  \
    const float uh2 = uf * fast_sigmoid(U[2]);                                  \
    const float uh3 = uf * fast_sigmoid(U[3]);                                  \
    __syncthreads(); /* bar A: s_rh complete */                                 \
    const half8v brh0 = __builtin_bit_cast(half8v,                              \
        *(const uint4*)&s_rh[trr]);                                             \
    const half8v brh1 = __builtin_bit_cast(half8v,                              \
        *(const uint4*)&s_rh[trr + 16]);                                        \
    C = MFMA16(Acn[2], brh0, C); C = MFMA16(Acn[3], brh1, C);                   \
    {                                                                           \
      const float c0 = fast_tanh(C[0]); hs4[0] = c0 + uh0 * (hs4[0] - c0);      \
      const float c1 = fast_tanh(C[1]); hs4[1] = c1 + uh1 * (hs4[1] - c1);      \
      const float c2 = fast_tanh(C[2]); hs4[2] = c2 + uh2 * (hs4[2] - c2);      \
      const float c3 = fast_tanh(C[3]); hs4[3] = c3 + uh3 * (hs4[3] - c3);      \
    }                                                                           \
    if (tcur < len_m) {                                                         \
      *(float4*)(orow + (size_t)tcur * Hn + 16 * w + 4 * kq) =                  \
          make_float4(hs4[0], hs4[1], hs4[2], hs4[3]);                          \
    }                                                                           \
    s_hh[trw + 0] = pk16(hs4[0], hs4[1]);                                       \
    s_hh[trw + 1] = pk16(hs4[2], hs4[3]);                                       \
    __syncthreads(); /* bar B: s_hh complete */                                 \
    bh0 = __builtin_bit_cast(half8v, *(const uint4*)&s_hh[trr]);                \
    bh1 = __builtin_bit_cast(half8v, *(const uint4*)&s_hh[trr + 16]);           \
  }

__global__ __launch_bounds__(256, 1)
void augru_fused16x4(const float* __restrict__ x,    // [B,T,64]
                     const int*   __restrict__ slen, // [B]
                     const float* __restrict__ att,  // [B,T]
                     const float* __restrict__ gk,   // [128][128]
                     const float* __restrict__ gb,   // [128]
                     const float* __restrict__ ck,   // [128][64]
                     const float* __restrict__ cb,   // [64]
                     float*       __restrict__ out,  // [B,T,64]
                     int B)
{
    const int tid  = threadIdx.x;
    const int w    = tid >> 6;      // wave id 0..3 = gate-column tile
    const int lane = tid & 63;
    const int lm   = lane & 15;     // batch row within group
    const int kq   = lane >> 4;     // K quadrant / output sub-column

    const int b0    = blockIdx.x * 16;
    const int brow  = b0 + lm;
    const int browc = min(brow, B - 1);
    const int len_m = (brow < B) ? slen[brow] : 0;

    // wave-wide max sequence length (same 16 rows in every wave)
    int Lmax = len_m;
#pragma unroll
    for (int off = 32; off; off >>= 1) Lmax = max(Lmax, __shfl_xor(Lmax, off));

    __shared__ uint s_rh[16 * 36];   // 2304 B transpose scratch (r*h)
    __shared__ uint s_hh[16 * 36];   // 2304 B transpose scratch (h)

    // LDS addressing: row m stride 36 dwords (pad spreads banks)
    const int trw = lm * 36 + 8 * w + 2 * kq;  // write base (this wave's cols)
    const int trr = lm * 36 + 4 * kq;          // read base (full-K B'-frag)

    // ---- persistent weight A'-fragments + bias C-inits for THIS wave's tile ----
    half8v Ar[4], Au[4], Acn[4];
#pragma unroll
    for (int kc = 0; kc < 4; ++kc) {
        half8v fr, fu, fc;
#pragma unroll
        for (int e = 0; e < 8; ++e) {
            const int k = kc * 32 + kq * 8 + e;
            fr[e] = (_Float16)gk[k * 128 + 16 * w + lm];
            fu[e] = (_Float16)gk[k * 128 + 64 + 16 * w + lm];
            fc[e] = (_Float16)ck[k * 64 + 16 * w + lm];
        }
        Ar[kc] = fr; Au[kc] = fu; Acn[kc] = fc;
    }
    const f32x4 biasR = {gb[16 * w + 4 * kq + 0], gb[16 * w + 4 * kq + 1],
                         gb[16 * w + 4 * kq + 2], gb[16 * w + 4 * kq + 3]};
    const f32x4 biasU = {gb[64 + 16 * w + 4 * kq + 0], gb[64 + 16 * w + 4 * kq + 1],
                         gb[64 + 16 * w + 4 * kq + 2], gb[64 + 16 * w + 4 * kq + 3]};
    const f32x4 biasC = {cb[16 * w + 4 * kq + 0], cb[16 * w + 4 * kq + 1],
                         cb[16 * w + 4 * kq + 2], cb[16 * w + 4 * kq + 3]};

    const float* xb   = x   + (size_t)browc * Tn * Dn;
    const float* ab   = att + (size_t)browc * Tn;
    float*       orow = out + (size_t)brow * Tn * Hn;   // only used if valid

    // ---- state: 4 h values per lane (row lm, cols 16w+4kq..+3) ----
    float hs4[4] = {0.f, 0.f, 0.f, 0.f};
    half8v bh0 = half8v{0}, bh1 = half8v{0};

    // ---- 2-deep named X/att prefetch slots ----
    float4 qA0{}, qA1{}, qA2{}, qA3{}, qB0{}, qB1{}, qB2{}, qB3{};
    float aA = 0.f, aB = 0.f;

    if (Lmax > 0) {
        if (0 < len_m) {
            const float* xr = xb + kq * 8;
            qA0 = *(const float4*)(xr);      qA1 = *(const float4*)(xr + 4);
            qA2 = *(const float4*)(xr + 32); qA3 = *(const float4*)(xr + 36);
        }
        aA = ab[0];
        const int t1 = min(1, Lmax - 1);
        if (t1 < len_m) {
            const float* xr = xb + (size_t)t1 * Dn + kq * 8;
            qB0 = *(const float4*)(xr);      qB1 = *(const float4*)(xr + 4);
            qB2 = *(const float4*)(xr + 32); qB3 = *(const float4*)(xr + 36);
        }
        aB = ab[t1];

        int t = 0;
        for (;;) {
            AUGRU_STEP(qA0, qA1, qA2, qA3, aA, t);
            if (++t >= Lmax) break;
            AUGRU_STEP(qB0, qB1, qB2, qB3, aB, t);
            if (++t >= Lmax) break;
        }
    }

    // ---- zero tails: out[b, len:T, :] = 0, all 256 threads per row ----
#pragma unroll 1
    for (int mm = 0; mm < 16; ++mm) {
        const int row = b0 + mm;
        if (row >= B) break;
        const int L = __shfl(len_m, mm);
        float* tail = out + ((size_t)row * Tn + L) * Hn;
        const int total = (Tn - L) * Hn;
        for (int i = tid * 4; i < total; i += 1024) {
            *(float4*)(tail + i) = make_float4(0.f, 0.f, 0.f, 0.f);
        }
    }
}

extern "C" void kernel_launch(void* const* d_in, const int* in_sizes, int n_in,
                              void* d_out, int out_size, void* d_ws, size_t ws_size,
                              hipStream_t stream) {
    const float* x    = (const float*)d_in[0];
    const int*   slen = (const int*)  d_in[1];
    const float* att  = (const float*)d_in[2];
    const float* gk   = (const float*)d_in[3];
    const float* gb   = (const float*)d_in[4];
    const float* ck   = (const float*)d_in[5];
    const float* cb   = (const float*)d_in[6];
    float* out = (float*)d_out;

    const int B = in_sizes[1];  // 2048
    const int grid = (B + 15) / 16;
    augru_fused16x4<<<grid, 256, 0, stream>>>(x, slen, att, gk, gb, ck, cb, out, B);
}